// Round 1
// baseline (413.111 us; speedup 1.0000x reference)
//
#include <hip/hip_runtime.h>
#include <hip/hip_bf16.h>

using bf16 = __hip_bfloat16;

using frag_ab = __attribute__((ext_vector_type(8))) short;  // 8 bf16 = 4 VGPRs
using frag_cd = __attribute__((ext_vector_type(4))) float;  // 4 fp32 acc

__device__ __forceinline__ unsigned short f2bu(float f) {
    bf16 h = __float2bfloat16(f);
    return *(unsigned short*)&h;
}

__device__ __forceinline__ void st_c(float* p, float v) { *p = v; }
__device__ __forceinline__ void st_c(bf16* p, float v)  { *p = __float2bfloat16(v); }

// 16B-per-lane async global->LDS. Per-wave LDS dest = uniform base + lane*16.
__device__ __forceinline__ void load16(const bf16* g, bf16* l) {
    __builtin_amdgcn_global_load_lds(
        (const __attribute__((address_space(1))) unsigned int*)g,
        (__attribute__((address_space(3))) unsigned int*)l,
        16, 0, 0);
}

// ---------------------------------------------------------------------------
// 256x256 8-phase GEMM (T2+T3+T4+T5 template, reconstructed from the guide).
// C[m][n] = scale * sum_k A[m][k]*B[n][k] (+bias[n]) (+ -inf where mask[n]).
// 512 threads = 8 waves (2M x 4N), per-wave 128x64 output, BK=64.
// LDS = 4-slot ring, slot = (K-tile, 32-k-slice): A[256][32] + B[256][32] = 32KB.
// Phase p (0..7): reads slot p>>1, qm=p&1 half (8 ds_read_b128 -> 16 MFMA);
// stages the half-slot whose LAST read finished at phase p-1 (race-free by
// issue order). vmcnt(4) at phases 1 and 5 => every refill landed >=1 phase
// before its next read (hand-verified incl. prologue + peeled last iter).
// Bank swizzle: 16B-chunk ^= (lrow&3)^((lrow>>2)&3) (involution), applied to
// the per-lane GLOBAL source so global_load_lds dest stays linear (rule #21).
// ---------------------------------------------------------------------------
template <typename TC, bool HAS_BIAS, bool MASK>
__global__ __launch_bounds__(512, 2)
void gemm8p(const bf16* __restrict__ A, const bf16* __restrict__ B,
            const float* __restrict__ bias, const int* __restrict__ mask,
            TC* __restrict__ C, int K, int lda, int ldb, int ldc,
            long sA, long sB, long sC, long sM, float scale)
{
    __shared__ short lds[65536];   // 4 slots x 16384 shorts = 128 KiB

    const int bz = blockIdx.z;
    const bf16* Ab = A + (long)bz * sA;
    const bf16* Bb = B + (long)bz * sB;
    TC* Cb = C + (long)bz * sC;
    const int* maskb = MASK ? (mask + (long)bz * sM) : nullptr;

    const int t    = threadIdx.x;
    const int wid  = t >> 6;
    const int lane = t & 63;
    const int m0 = blockIdx.x * 256;
    const int n0 = blockIdx.y * 256;
    const int wr = wid >> 2;       // 0..1  (M wave)
    const int wc = wid & 3;        // 0..3  (N wave)
    const int lrow = lane & 15;
    const int quad = lane >> 4;

    // reader-side swizzled 16B chunk (lane-only; row bits 0..3 == lrow bits)
    const int rco   = ((quad ^ (lrow & 3) ^ ((lrow >> 2) & 3)) & 3) * 8;  // shorts
    const int a_off = wr * 4096 + lrow * 32 + rco;   // + qm*2048 + i*512
    const int b_off = wc * 2048 + lrow * 32 + rco;   // + j*512 (B part +8192)

    // staging: instr q = wid*2+l covers LDS rows q*16..+16 (1024B linear).
    // global source pre-swizzled: k-chunk = (lane&3)^((lane>>2)&3)^(lane>>4).
    const int srow = wid * 32 + (lane >> 2);
    const int gk   = (((lane & 3) ^ ((lane >> 2) & 3) ^ (lane >> 4)) & 3) * 8;
    const bf16* srcA0 = Ab + (long)(m0 + srow) * lda + gk;
    const bf16* srcA1 = Ab + (long)(m0 + srow + 16) * lda + gk;
    const bf16* srcB0 = Bb + (long)(n0 + srow) * ldb + gk;
    const bf16* srcB1 = Bb + (long)(n0 + srow + 16) * ldb + gk;
    const int dst0 = wid * 1024 + lane * 8;          // shorts

    frag_cd acc[8][4] = {};

#define STG(SLOT, PART, K0)                                                     \
    do {                                                                        \
        load16((PART ? srcB0 : srcA0) + (K0),                                   \
               (bf16*)&lds[(SLOT) * 16384 + (PART) * 8192 + dst0]);             \
        load16((PART ? srcB1 : srcA1) + (K0),                                   \
               (bf16*)&lds[(SLOT) * 16384 + (PART) * 8192 + dst0 + 512]);       \
    } while (0)

#define PHASE(SLOT, QM, DO_STG, SSLOT, SPART, SK0, VM)                          \
    do {                                                                        \
        frag_ab af_[4], bf_[4];                                                 \
        _Pragma("unroll")                                                       \
        for (int i_ = 0; i_ < 4; ++i_)                                          \
            af_[i_] = *(const frag_ab*)&lds[(SLOT) * 16384 + a_off +            \
                                            (QM) * 2048 + i_ * 512];            \
        _Pragma("unroll")                                                       \
        for (int j_ = 0; j_ < 4; ++j_)                                          \
            bf_[j_] = *(const frag_ab*)&lds[(SLOT) * 16384 + 8192 + b_off +     \
                                            j_ * 512];                          \
        if (DO_STG) STG(SSLOT, SPART, SK0);                                     \
        if ((VM) == 1) asm volatile("s_waitcnt vmcnt(4)" ::: "memory");         \
        if ((VM) == 2) asm volatile("s_waitcnt vmcnt(0)" ::: "memory");         \
        __builtin_amdgcn_sched_barrier(0);                                      \
        __builtin_amdgcn_s_barrier();                                           \
        asm volatile("s_waitcnt lgkmcnt(0)" ::: "memory");                      \
        __builtin_amdgcn_sched_barrier(0);                                      \
        __builtin_amdgcn_s_setprio(1);                                          \
        _Pragma("unroll")                                                       \
        for (int i_ = 0; i_ < 4; ++i_)                                          \
            _Pragma("unroll")                                                   \
            for (int j_ = 0; j_ < 4; ++j_)                                      \
                acc[(QM) * 4 + i_][j_] = __builtin_amdgcn_mfma_f32_16x16x32_bf16( \
                    af_[i_], bf_[j_], acc[(QM) * 4 + i_][j_], 0, 0, 0);         \
        __builtin_amdgcn_s_setprio(0);                                          \
        __builtin_amdgcn_sched_barrier(0);                                      \
        __builtin_amdgcn_s_barrier();                                           \
    } while (0)

    // prologue: slot0 = tile0 ks0, slot1 = tile0 ks1, slot2 = tile1 ks0
    STG(0, 0, 0);  STG(0, 1, 0);
    STG(1, 0, 32); STG(1, 1, 32);
    STG(2, 0, 64); STG(2, 1, 64);
    asm volatile("s_waitcnt vmcnt(4)" ::: "memory");   // slots 0,1 landed
    __builtin_amdgcn_sched_barrier(0);
    __builtin_amdgcn_s_barrier();
    __builtin_amdgcn_sched_barrier(0);

    const int NI = K >> 7;   // 128 K per iteration (2 K-tiles); NI >= 2 here
    for (int it = 0; it < NI - 1; ++it) {
        const int kb = it << 7;
        PHASE(0, 0, 1, 3, 0, kb + 96,  0);   // stage slot3 = tile 2i+1 ks1
        PHASE(0, 1, 1, 3, 1, kb + 96,  1);   // vmcnt(4)
        PHASE(1, 0, 1, 0, 0, kb + 128, 0);   // stage slot0 = tile 2i+2 ks0
        PHASE(1, 1, 1, 0, 1, kb + 128, 0);
        PHASE(2, 0, 1, 1, 0, kb + 160, 0);   // stage slot1 = tile 2i+2 ks1
        PHASE(2, 1, 1, 1, 1, kb + 160, 1);   // vmcnt(4)
        PHASE(3, 0, 1, 2, 0, kb + 192, 0);   // stage slot2 = tile 2i+3 ks0
        PHASE(3, 1, 1, 2, 1, kb + 192, 0);
    }
    {   // peeled last iteration: only slot3 completion staged; drain at ph5
        const int kb = (NI - 1) << 7;
        PHASE(0, 0, 1, 3, 0, kb + 96, 0);
        PHASE(0, 1, 1, 3, 1, kb + 96, 1);
        PHASE(1, 0, 0, 0, 0, 0, 0);
        PHASE(1, 1, 0, 0, 0, 0, 0);
        PHASE(2, 0, 0, 0, 0, 0, 0);
        PHASE(2, 1, 0, 0, 0, 0, 2);          // vmcnt(0): slot3 landed
        PHASE(3, 0, 0, 0, 0, 0, 0);
        PHASE(3, 1, 0, 0, 0, 0, 0);
    }
#undef PHASE
#undef STG

    // epilogue: C/D layout col=lane&15, row=quad*4+reg  [m89-verified]
#pragma unroll
    for (int j = 0; j < 4; ++j) {
        const int col = n0 + wc * 64 + j * 16 + lrow;
        const float bv = HAS_BIAS ? bias[col] : 0.0f;
        const bool msk = MASK ? (maskb[col] != 0) : false;
#pragma unroll
        for (int ai = 0; ai < 8; ++ai) {
            const int rbase = m0 + wr * 128 + ai * 16 + quad * 4;
#pragma unroll
            for (int r = 0; r < 4; ++r) {
                float v = acc[ai][j][r] * scale + bv;
                if (MASK && msk) v = -INFINITY;
                st_c(&Cb[(long)(rbase + r) * ldc + col], v);
            }
        }
    }
}

// fp32 X[b][s][h] -> bf16 Xb[b][s][h] and bf16 XT[b][h][s], 64x64 tiles.
__global__ __launch_bounds__(256)
void convert_transpose(const float* __restrict__ X, bf16* __restrict__ Xb,
                       bf16* __restrict__ XT, int S, int H)
{
    __shared__ unsigned short tile[64][72];
    const int b = blockIdx.z;
    const float* Xp = X + (long)b * S * H;
    bf16* Xbp = Xb + (long)b * S * H;
    bf16* XTp = XT + (long)b * H * S;
    const int h0 = blockIdx.x * 64, s0 = blockIdx.y * 64;
    const int t = threadIdx.x;
    const int r  = t >> 4;
    const int c4 = (t & 15) * 4;

#pragma unroll
    for (int p = 0; p < 4; ++p) {
        const int row = r + p * 16;
        const float4 v = *(const float4*)&Xp[(long)(s0 + row) * H + h0 + c4];
        ushort4 u;
        u.x = f2bu(v.x); u.y = f2bu(v.y); u.z = f2bu(v.z); u.w = f2bu(v.w);
        *(ushort4*)&tile[row][c4] = u;
        *(ushort4*)&Xbp[(long)(s0 + row) * H + h0 + c4] = u;
    }
    __syncthreads();
#pragma unroll
    for (int p = 0; p < 4; ++p) {
        const int hrow = r + p * 16;
        ushort4 u;
        u.x = tile[c4 + 0][hrow];
        u.y = tile[c4 + 1][hrow];
        u.z = tile[c4 + 2][hrow];
        u.w = tile[c4 + 3][hrow];
        *(ushort4*)&XTp[(long)(h0 + hrow) * S + s0 + c4] = u;
    }
}

// both weight matrices -> bf16, contiguous out [2*H*H]
__global__ __launch_bounds__(256)
void convert_w2(const float* __restrict__ wa, const float* __restrict__ wb,
                bf16* __restrict__ out, int n4each)
{
    const int i = blockIdx.x * 256 + threadIdx.x;
    const bool second = i >= n4each;
    const float* src = second ? wb : wa;
    const int j = second ? i - n4each : i;
    const float4 v = ((const float4*)src)[j];
    ushort4 u;
    u.x = f2bu(v.x); u.y = f2bu(v.y); u.z = f2bu(v.z); u.w = f2bu(v.w);
    ((ushort4*)out)[i] = u;
}

__global__ __launch_bounds__(256)
void pack_bias(const float* __restrict__ qb, const float* __restrict__ kb,
               float* __restrict__ out, int H)
{
    const int i = blockIdx.x * 256 + threadIdx.x;
    out[i] = (i < H) ? qb[i] : kb[i - H];
}

// In-place masked softmax over rows (Slen=2048 bf16). Mask pre-applied as -inf.
__global__ __launch_bounds__(256)
void softmax_kernel(bf16* __restrict__ Smat, int Slen)
{
    const int row = blockIdx.x;
    bf16* srow = Smat + (long)row * Slen;

    const int t    = threadIdx.x;
    const int lane = t & 63;
    const int wid  = t >> 6;

    ushort4 u0 = ((const ushort4*)srow)[t * 2];
    ushort4 u1 = ((const ushort4*)srow)[t * 2 + 1];

    float vals[8];
    {
        const unsigned short us[8] = {u0.x, u0.y, u0.z, u0.w, u1.x, u1.y, u1.z, u1.w};
#pragma unroll
        for (int i = 0; i < 8; ++i) {
            unsigned int w = (unsigned int)us[i] << 16;
            vals[i] = *(float*)&w;
        }
    }

    float mx = vals[0];
#pragma unroll
    for (int i = 1; i < 8; ++i) mx = fmaxf(mx, vals[i]);

    __shared__ float red[4];
#pragma unroll
    for (int o = 32; o > 0; o >>= 1) mx = fmaxf(mx, __shfl_xor(mx, o, 64));
    if (lane == 0) red[wid] = mx;
    __syncthreads();
    mx = fmaxf(fmaxf(red[0], red[1]), fmaxf(red[2], red[3]));
    __syncthreads();

    float sum = 0.0f;
#pragma unroll
    for (int i = 0; i < 8; ++i) {
        const float e = __expf(vals[i] - mx);   // exp(-inf - mx) = 0
        vals[i] = e;
        sum += e;
    }
#pragma unroll
    for (int o = 32; o > 0; o >>= 1) sum += __shfl_xor(sum, o, 64);
    if (lane == 0) red[wid] = sum;
    __syncthreads();
    sum = red[0] + red[1] + red[2] + red[3];

    const float inv = 1.0f / sum;
    ushort4 o0, o1;
    o0.x = f2bu(vals[0] * inv); o0.y = f2bu(vals[1] * inv);
    o0.z = f2bu(vals[2] * inv); o0.w = f2bu(vals[3] * inv);
    o1.x = f2bu(vals[4] * inv); o1.y = f2bu(vals[5] * inv);
    o1.z = f2bu(vals[6] * inv); o1.w = f2bu(vals[7] * inv);
    ((ushort4*)srow)[t * 2]     = o0;
    ((ushort4*)srow)[t * 2 + 1] = o1;
}

extern "C" void kernel_launch(void* const* d_in, const int* in_sizes, int n_in,
                              void* d_out, int out_size, void* d_ws, size_t ws_size,
                              hipStream_t stream)
{
    const float* hidden = (const float*)d_in[0];
    const int*   mask   = (const int*)d_in[1];
    const float* Wq_w   = (const float*)d_in[2];
    const float* Wq_b   = (const float*)d_in[3];
    const float* Wk_w   = (const float*)d_in[4];
    const float* Wk_b   = (const float*)d_in[5];
    float* out = (float*)d_out;

    const int B = 8, S = 2048, H = 1024;
    const int M = B * S;               // 16384
    const long MH = (long)M * H;       // 16.7M elems

    // ws (bf16 elems): QK[M][2H] (67MB) | XbT (33.5MB) | Sb (67MB)
    // Xb + Wb (stacked weights) + packed bias aliased inside Sb (dead before scores).
    bf16* QK  = (bf16*)d_ws;
    bf16* XbT = QK + MH * 2;
    bf16* Sb  = XbT + MH;
    bf16* Xb  = Sb;                    // aliased
    bf16* Wb  = Xb + MH;               // [2H][H] = Wq stacked on Wk
    float* biasP = (float*)(Wb + 2L * H * H);  // 2048 floats

    const dim3 blk(256);
    const dim3 blk512(512);

    convert_transpose<<<dim3(H / 64, S / 64, B), blk, 0, stream>>>(hidden, Xb, XbT, S, H);
    convert_w2<<<dim3(2 * H * H / 1024), blk, 0, stream>>>(Wq_w, Wk_w, Wb, H * H / 4);
    pack_bias<<<dim3(2 * H / 256), blk, 0, stream>>>(Wq_b, Wk_b, biasP, H);

    // QK = Xb @ [Wq;Wk]^T + [bq;bk]   (merged, N = 2H) : 16384 x 2048, K=1024
    gemm8p<bf16, true, false><<<dim3(M / 256, 2 * H / 256, 1), blk512, 0, stream>>>(
        Xb, Wb, biasP, nullptr, QK, H, H, H, 2 * H, 0, 0, 0, 0, 1.0f);

    // Scores_b = (Q_b @ K_b^T)/32, mask applied as -inf in epilogue : 2048x2048, K=1024
    gemm8p<bf16, false, true><<<dim3(S / 256, S / 256, B), blk512, 0, stream>>>(
        QK, QK + H, nullptr, mask, Sb, H, 2 * H, 2 * H, S,
        (long)S * 2 * H, (long)S * 2 * H, (long)S * S, S, 1.0f / 32.0f);

    // softmax in place (mask already -inf)
    softmax_kernel<<<dim3(B * S), blk, 0, stream>>>(Sb, S);

    // Out_b = P_b @ X_b  (B operand = XbT, k-contig) : 2048x1024, K=2048
    gemm8p<float, false, false><<<dim3(S / 256, H / 256, B), blk512, 0, stream>>>(
        Sb, XbT, nullptr, nullptr, out, S, S, S, H,
        (long)S * S, (long)H * S, (long)S * H, 0, 1.0f);
}

// Round 2
// 392.996 us; speedup vs baseline: 1.0512x; 1.0512x over previous
//
#include <hip/hip_runtime.h>
#include <hip/hip_bf16.h>

using bf16 = __hip_bfloat16;

using frag_ab = __attribute__((ext_vector_type(8))) short;  // 8 bf16 = 4 VGPRs
using frag_cd = __attribute__((ext_vector_type(4))) float;  // 4 fp32 acc

__device__ __forceinline__ unsigned short f2bu(float f) {
    bf16 h = __float2bfloat16(f);
    return *(unsigned short*)&h;
}

__device__ __forceinline__ void st_c(float* p, float v) { *p = v; }
__device__ __forceinline__ void st_c(bf16* p, float v)  { *p = __float2bfloat16(v); }

// 16B-per-lane async global->LDS. Per-wave LDS dest = uniform base + lane*16.
__device__ __forceinline__ void load16(const bf16* g, bf16* l) {
    __builtin_amdgcn_global_load_lds(
        (const __attribute__((address_space(1))) unsigned int*)g,
        (__attribute__((address_space(3))) unsigned int*)l,
        16, 0, 0);
}

// ---------------------------------------------------------------------------
// 256x256 8-phase GEMM, round 2.
// Fixes vs round 1 (which ran at baseline speed):
//  * Bank swizzle: rotate chunk = (quad + (row>>1)) & 3 -- the EXACT pattern
//    that measured 0 SQ_LDS_BANK_CONFLICT in the round-0 kernel (the XOR
//    variant measured exactly +4 conflict-cycles per ds_read_b128).
//  * vmcnt checkpoints moved to the END barrier of every odd phase with N=8:
//    each slot's staging (issued 4-5 phases = ~600-750cy earlier) is drained
//    one barrier before its first read, instead of ~2.5 phases (stall).
//    Steady-state invariant (hand-verified): iteration entry = 8 outstanding
//    {slot1,slot2}; each vmcnt(8) drains exactly the slot read 2 phases later.
//    Peeled last iter: vmcnt 8 -> 4 -> 0.
// Ring: 4 slots, slot = (K-tile, 32-k-slice), slot s read at phases 2s,2s+1,
// restaged at phases 2s+2,2s+3 (issue-after-last-read => race-free: the end
// barrier of phase 2s+1 is crossed only after every wave's lgkmcnt(0)).
// ---------------------------------------------------------------------------
template <typename TC, bool HAS_BIAS, bool MASK>
__global__ __launch_bounds__(512, 2)
void gemm8p(const bf16* __restrict__ A, const bf16* __restrict__ B,
            const float* __restrict__ bias, const int* __restrict__ mask,
            TC* __restrict__ C, int K, int lda, int ldb, int ldc,
            long sA, long sB, long sC, long sM, float scale)
{
    __shared__ short lds[65536];   // 4 slots x 16384 shorts = 128 KiB

    const int bz = blockIdx.z;
    const bf16* Ab = A + (long)bz * sA;
    const bf16* Bb = B + (long)bz * sB;
    TC* Cb = C + (long)bz * sC;
    const int* maskb = MASK ? (mask + (long)bz * sM) : nullptr;

    const int t    = threadIdx.x;
    const int wid  = t >> 6;
    const int lane = t & 63;
    const int m0 = blockIdx.x * 256;
    const int n0 = blockIdx.y * 256;
    const int wr = wid >> 2;       // 0..1  (M wave)
    const int wc = wid & 3;        // 0..3  (N wave)
    const int lrow = lane & 15;
    const int quad = lane >> 4;

    // reader-side swizzled 16B chunk: rotate by (row>>1)&3 (row bits 1..2 ==
    // lrow bits 1..2 -- all other row terms are multiples of 16).
    const int rco   = ((quad + ((lrow >> 1) & 3)) & 3) * 8;   // shorts
    const int a_off = wr * 4096 + lrow * 32 + rco;   // + qm*2048 + i*512
    const int b_off = wc * 2048 + lrow * 32 + rco;   // + j*512 (B part +8192)

    // staging: instr covers 16 LDS rows (1024B linear); lane l -> row l>>2,
    // chunk l&3. Global source pre-rotated: chunk_g = (c - (row>>1)) & 3.
    const int srow = wid * 32 + (lane >> 2);
    const int gk   = (((lane & 3) - (lane >> 3)) & 3) * 8;
    const bf16* srcA0 = Ab + (long)(m0 + srow) * lda + gk;
    const bf16* srcA1 = Ab + (long)(m0 + srow + 16) * lda + gk;
    const bf16* srcB0 = Bb + (long)(n0 + srow) * ldb + gk;
    const bf16* srcB1 = Bb + (long)(n0 + srow + 16) * ldb + gk;
    const int dst0 = wid * 1024 + lane * 8;          // shorts

    frag_cd acc[8][4] = {};

#define STG(SLOT, PART, K0)                                                     \
    do {                                                                        \
        load16((PART ? srcB0 : srcA0) + (K0),                                   \
               (bf16*)&lds[(SLOT) * 16384 + (PART) * 8192 + dst0]);             \
        load16((PART ? srcB1 : srcA1) + (K0),                                   \
               (bf16*)&lds[(SLOT) * 16384 + (PART) * 8192 + dst0 + 512]);       \
    } while (0)

// VMN: -1 = no wait; else s_waitcnt vmcnt(VMN) before the END barrier.
#define PHASE(SLOT, QM, DO_STG, SSLOT, SPART, SK0, VMN)                         \
    do {                                                                        \
        frag_ab af_[4], bf_[4];                                                 \
        _Pragma("unroll")                                                       \
        for (int i_ = 0; i_ < 4; ++i_)                                          \
            af_[i_] = *(const frag_ab*)&lds[(SLOT) * 16384 + a_off +            \
                                            (QM) * 2048 + i_ * 512];            \
        _Pragma("unroll")                                                       \
        for (int j_ = 0; j_ < 4; ++j_)                                          \
            bf_[j_] = *(const frag_ab*)&lds[(SLOT) * 16384 + 8192 + b_off +     \
                                            j_ * 512];                          \
        if (DO_STG) STG(SSLOT, SPART, SK0);                                     \
        __builtin_amdgcn_sched_barrier(0);                                      \
        __builtin_amdgcn_s_barrier();                                           \
        asm volatile("s_waitcnt lgkmcnt(0)" ::: "memory");                      \
        __builtin_amdgcn_sched_barrier(0);                                      \
        __builtin_amdgcn_s_setprio(1);                                          \
        _Pragma("unroll")                                                       \
        for (int i_ = 0; i_ < 4; ++i_)                                          \
            _Pragma("unroll")                                                   \
            for (int j_ = 0; j_ < 4; ++j_)                                      \
                acc[(QM) * 4 + i_][j_] = __builtin_amdgcn_mfma_f32_16x16x32_bf16( \
                    af_[i_], bf_[j_], acc[(QM) * 4 + i_][j_], 0, 0, 0);         \
        __builtin_amdgcn_s_setprio(0);                                          \
        __builtin_amdgcn_sched_barrier(0);                                      \
        if ((VMN) == 8) asm volatile("s_waitcnt vmcnt(8)" ::: "memory");        \
        else if ((VMN) == 4) asm volatile("s_waitcnt vmcnt(4)" ::: "memory");   \
        else if ((VMN) == 0) asm volatile("s_waitcnt vmcnt(0)" ::: "memory");   \
        __builtin_amdgcn_sched_barrier(0);                                      \
        __builtin_amdgcn_s_barrier();                                           \
    } while (0)

    // prologue: slot0 = tile0 ks0, slot1 = tile0 ks1, slot2 = tile1 ks0
    STG(0, 0, 0);  STG(0, 1, 0);
    STG(1, 0, 32); STG(1, 1, 32);
    STG(2, 0, 64); STG(2, 1, 64);
    asm volatile("s_waitcnt vmcnt(8)" ::: "memory");   // slot0 landed
    __builtin_amdgcn_sched_barrier(0);
    __builtin_amdgcn_s_barrier();
    __builtin_amdgcn_sched_barrier(0);

    const int NI = K >> 7;   // 128 K per iteration (2 K-tiles); NI >= 2 here
    for (int it = 0; it < NI - 1; ++it) {
        const int kb = it << 7;
        PHASE(0, 0, 1, 3, 0, kb + 96,  -1);  // stage slot3 = tile 2i+1 ks1
        PHASE(0, 1, 1, 3, 1, kb + 96,   8);  // drain slot1 (read ph2-3)
        PHASE(1, 0, 1, 0, 0, kb + 128, -1);  // stage slot0 = tile 2i+2 ks0
        PHASE(1, 1, 1, 0, 1, kb + 128,  8);  // drain slot2 (read ph4-5)
        PHASE(2, 0, 1, 1, 0, kb + 160, -1);  // stage slot1 = tile 2i+2 ks1
        PHASE(2, 1, 1, 1, 1, kb + 160,  8);  // drain slot3 (read ph6-7)
        PHASE(3, 0, 1, 2, 0, kb + 192, -1);  // stage slot2 = tile 2i+3 ks0
        PHASE(3, 1, 1, 2, 1, kb + 192,  8);  // drain slot0 (read next ph0-1)
    }
    {   // peeled last iteration: only slot3 (this iter's ks1) still staged
        const int kb = (NI - 1) << 7;
        PHASE(0, 0, 1, 3, 0, kb + 96, -1);
        PHASE(0, 1, 1, 3, 1, kb + 96,  8);   // drain slot1
        PHASE(1, 0, 0, 0, 0, 0, -1);
        PHASE(1, 1, 0, 0, 0, 0,  4);         // drain slot2
        PHASE(2, 0, 0, 0, 0, 0, -1);
        PHASE(2, 1, 0, 0, 0, 0,  0);         // drain slot3
        PHASE(3, 0, 0, 0, 0, 0, -1);
        PHASE(3, 1, 0, 0, 0, 0, -1);
    }
#undef PHASE
#undef STG

    // epilogue: C/D layout col=lane&15, row=quad*4+reg  [m89-verified]
#pragma unroll
    for (int j = 0; j < 4; ++j) {
        const int col = n0 + wc * 64 + j * 16 + lrow;
        const float bv = HAS_BIAS ? bias[col] : 0.0f;
        const bool msk = MASK ? (maskb[col] != 0) : false;
#pragma unroll
        for (int ai = 0; ai < 8; ++ai) {
            const int rbase = m0 + wr * 128 + ai * 16 + quad * 4;
#pragma unroll
            for (int r = 0; r < 4; ++r) {
                float v = acc[ai][j][r] * scale + bv;
                if (MASK && msk) v = -INFINITY;
                st_c(&Cb[(long)(rbase + r) * ldc + col], v);
            }
        }
    }
}

// fp32 X[b][s][h] -> bf16 Xb[b][s][h] and bf16 XT[b][h][s], 64x64 tiles.
__global__ __launch_bounds__(256)
void convert_transpose(const float* __restrict__ X, bf16* __restrict__ Xb,
                       bf16* __restrict__ XT, int S, int H)
{
    __shared__ unsigned short tile[64][72];
    const int b = blockIdx.z;
    const float* Xp = X + (long)b * S * H;
    bf16* Xbp = Xb + (long)b * S * H;
    bf16* XTp = XT + (long)b * H * S;
    const int h0 = blockIdx.x * 64, s0 = blockIdx.y * 64;
    const int t = threadIdx.x;
    const int r  = t >> 4;
    const int c4 = (t & 15) * 4;

#pragma unroll
    for (int p = 0; p < 4; ++p) {
        const int row = r + p * 16;
        const float4 v = *(const float4*)&Xp[(long)(s0 + row) * H + h0 + c4];
        ushort4 u;
        u.x = f2bu(v.x); u.y = f2bu(v.y); u.z = f2bu(v.z); u.w = f2bu(v.w);
        *(ushort4*)&tile[row][c4] = u;
        *(ushort4*)&Xbp[(long)(s0 + row) * H + h0 + c4] = u;
    }
    __syncthreads();
#pragma unroll
    for (int p = 0; p < 4; ++p) {
        const int hrow = r + p * 16;
        ushort4 u;
        u.x = tile[c4 + 0][hrow];
        u.y = tile[c4 + 1][hrow];
        u.z = tile[c4 + 2][hrow];
        u.w = tile[c4 + 3][hrow];
        *(ushort4*)&XTp[(long)(h0 + hrow) * S + s0 + c4] = u;
    }
}

// both weight matrices -> bf16, contiguous out [2*H*H]
__global__ __launch_bounds__(256)
void convert_w2(const float* __restrict__ wa, const float* __restrict__ wb,
                bf16* __restrict__ out, int n4each)
{
    const int i = blockIdx.x * 256 + threadIdx.x;
    const bool second = i >= n4each;
    const float* src = second ? wb : wa;
    const int j = second ? i - n4each : i;
    const float4 v = ((const float4*)src)[j];
    ushort4 u;
    u.x = f2bu(v.x); u.y = f2bu(v.y); u.z = f2bu(v.z); u.w = f2bu(v.w);
    ((ushort4*)out)[i] = u;
}

__global__ __launch_bounds__(256)
void pack_bias(const float* __restrict__ qb, const float* __restrict__ kb,
               float* __restrict__ out, int H)
{
    const int i = blockIdx.x * 256 + threadIdx.x;
    out[i] = (i < H) ? qb[i] : kb[i - H];
}

// In-place masked softmax over rows (Slen=2048 bf16). Mask pre-applied as -inf.
__global__ __launch_bounds__(256)
void softmax_kernel(bf16* __restrict__ Smat, int Slen)
{
    const int row = blockIdx.x;
    bf16* srow = Smat + (long)row * Slen;

    const int t    = threadIdx.x;
    const int lane = t & 63;
    const int wid  = t >> 6;

    ushort4 u0 = ((const ushort4*)srow)[t * 2];
    ushort4 u1 = ((const ushort4*)srow)[t * 2 + 1];

    float vals[8];
    {
        const unsigned short us[8] = {u0.x, u0.y, u0.z, u0.w, u1.x, u1.y, u1.z, u1.w};
#pragma unroll
        for (int i = 0; i < 8; ++i) {
            unsigned int w = (unsigned int)us[i] << 16;
            vals[i] = *(float*)&w;
        }
    }

    float mx = vals[0];
#pragma unroll
    for (int i = 1; i < 8; ++i) mx = fmaxf(mx, vals[i]);

    __shared__ float red[4];
#pragma unroll
    for (int o = 32; o > 0; o >>= 1) mx = fmaxf(mx, __shfl_xor(mx, o, 64));
    if (lane == 0) red[wid] = mx;
    __syncthreads();
    mx = fmaxf(fmaxf(red[0], red[1]), fmaxf(red[2], red[3]));
    __syncthreads();

    float sum = 0.0f;
#pragma unroll
    for (int i = 0; i < 8; ++i) {
        const float e = __expf(vals[i] - mx);   // exp(-inf - mx) = 0
        vals[i] = e;
        sum += e;
    }
#pragma unroll
    for (int o = 32; o > 0; o >>= 1) sum += __shfl_xor(sum, o, 64);
    if (lane == 0) red[wid] = sum;
    __syncthreads();
    sum = red[0] + red[1] + red[2] + red[3];

    const float inv = 1.0f / sum;
    ushort4 o0, o1;
    o0.x = f2bu(vals[0] * inv); o0.y = f2bu(vals[1] * inv);
    o0.z = f2bu(vals[2] * inv); o0.w = f2bu(vals[3] * inv);
    o1.x = f2bu(vals[4] * inv); o1.y = f2bu(vals[5] * inv);
    o1.z = f2bu(vals[6] * inv); o1.w = f2bu(vals[7] * inv);
    ((ushort4*)srow)[t * 2]     = o0;
    ((ushort4*)srow)[t * 2 + 1] = o1;
}

extern "C" void kernel_launch(void* const* d_in, const int* in_sizes, int n_in,
                              void* d_out, int out_size, void* d_ws, size_t ws_size,
                              hipStream_t stream)
{
    const float* hidden = (const float*)d_in[0];
    const int*   mask   = (const int*)d_in[1];
    const float* Wq_w   = (const float*)d_in[2];
    const float* Wq_b   = (const float*)d_in[3];
    const float* Wk_w   = (const float*)d_in[4];
    const float* Wk_b   = (const float*)d_in[5];
    float* out = (float*)d_out;

    const int B = 8, S = 2048, H = 1024;
    const int M = B * S;               // 16384
    const long MH = (long)M * H;       // 16.7M elems

    // ws (bf16 elems): QK[M][2H] (67MB) | XbT (33.5MB) | Sb (67MB)
    // Xb + Wb (stacked weights) + packed bias aliased inside Sb (dead before scores).
    bf16* QK  = (bf16*)d_ws;
    bf16* XbT = QK + MH * 2;
    bf16* Sb  = XbT + MH;
    bf16* Xb  = Sb;                    // aliased
    bf16* Wb  = Xb + MH;               // [2H][H] = Wq stacked on Wk
    float* biasP = (float*)(Wb + 2L * H * H);  // 2048 floats

    const dim3 blk(256);
    const dim3 blk512(512);

    convert_transpose<<<dim3(H / 64, S / 64, B), blk, 0, stream>>>(hidden, Xb, XbT, S, H);
    convert_w2<<<dim3(2 * H * H / 1024), blk, 0, stream>>>(Wq_w, Wk_w, Wb, H * H / 4);
    pack_bias<<<dim3(2 * H / 256), blk, 0, stream>>>(Wq_b, Wk_b, biasP, H);

    // QK = Xb @ [Wq;Wk]^T + [bq;bk]   (merged, N = 2H) : 16384 x 2048, K=1024
    gemm8p<bf16, true, false><<<dim3(M / 256, 2 * H / 256, 1), blk512, 0, stream>>>(
        Xb, Wb, biasP, nullptr, QK, H, H, H, 2 * H, 0, 0, 0, 0, 1.0f);

    // Scores_b = (Q_b @ K_b^T)/32, mask applied as -inf in epilogue : 2048x2048, K=1024
    gemm8p<bf16, false, true><<<dim3(S / 256, S / 256, B), blk512, 0, stream>>>(
        QK, QK + H, nullptr, mask, Sb, H, 2 * H, 2 * H, S,
        (long)S * 2 * H, (long)S * 2 * H, (long)S * S, S, 1.0f / 32.0f);

    // softmax in place (mask already -inf)
    softmax_kernel<<<dim3(B * S), blk, 0, stream>>>(Sb, S);

    // Out_b = P_b @ X_b  (B operand = XbT, k-contig) : 2048x1024, K=2048
    gemm8p<float, false, false><<<dim3(S / 256, H / 256, B), blk512, 0, stream>>>(
        Sb, XbT, nullptr, nullptr, out, S, S, S, H,
        (long)S * S, (long)H * S, (long)S * H, 0, 1.0f);
}

// Round 3
// 375.582 us; speedup vs baseline: 1.0999x; 1.0464x over previous
//
#include <hip/hip_runtime.h>
#include <hip/hip_bf16.h>

using bf16 = __hip_bfloat16;

using frag_ab = __attribute__((ext_vector_type(8))) short;  // 8 bf16 = 4 VGPRs
using frag_cd = __attribute__((ext_vector_type(4))) float;  // 4 fp32 acc

__device__ __forceinline__ unsigned short f2bu(float f) {
    bf16 h = __float2bfloat16(f);
    return *(unsigned short*)&h;
}

__device__ __forceinline__ void st_c(float* p, float v) { *p = v; }
__device__ __forceinline__ void st_c(bf16* p, float v)  { *p = __float2bfloat16(v); }

// 16B-per-lane async global->LDS. Per-wave LDS dest = uniform base + lane*16.
__device__ __forceinline__ void load16(const bf16* g, bf16* l) {
    __builtin_amdgcn_global_load_lds(
        (const __attribute__((address_space(1))) unsigned int*)g,
        (__attribute__((address_space(3))) unsigned int*)l,
        16, 0, 0);
}

// ---------------------------------------------------------------------------
// 256x256 8-phase GEMM, round 3: fragment READ-AHEAD.
// Round-2 counters showed MfmaUtil 29%: ds_reads (585cy/phase/CU) sat inside
// the same-phase ds->lgkmcnt(0)->MFMA chain, serializing LDS and MFMA pipes.
// Now: phase p issues the ds_reads for cluster p+1 into double-buffered
// fragment registers (A0/A1 per-phase parity, B0/B1 per-slot parity; B loaded
// once per slot and reused by both its clusters -> 48KiB/phase LDS, hidden
// under the 620cy MFMA window). Compiler inserts the counted lgkmcnt(4/8)
// before each cluster (no manual lgkm; sched_barrier(0) fences pin order).
// One barrier per phase (end): write-after-read safe because slot s's last
// reader (batch 2s+1) is lgkm-complete in every wave before that wave crosses
// the end-barrier of phase 2s+1, and slot s's restage is issued at phase 2s+2.
// vmcnt(6) before the end-barrier of even phases drains exactly the slot
// staged 4 phases earlier, one barrier before its read-issue (hand-verified
// for prologue, steady state, and the peeled tail: 6/6/6/6, peel 6/4/0).
// ---------------------------------------------------------------------------
template <typename TC, bool HAS_BIAS, bool MASK>
__global__ __launch_bounds__(512, 2)
void gemm8p(const bf16* __restrict__ A, const bf16* __restrict__ B,
            const float* __restrict__ bias, const int* __restrict__ mask,
            TC* __restrict__ C, int K, int lda, int ldb, int ldc,
            long sA, long sB, long sC, long sM, float scale)
{
    __shared__ short lds[65536];   // 4 slots x 16384 shorts = 128 KiB

    const int bz = blockIdx.z;
    const bf16* Ab = A + (long)bz * sA;
    const bf16* Bb = B + (long)bz * sB;
    TC* Cb = C + (long)bz * sC;
    const int* maskb = MASK ? (mask + (long)bz * sM) : nullptr;

    const int t    = threadIdx.x;
    const int wid  = t >> 6;
    const int lane = t & 63;
    const int m0 = blockIdx.x * 256;
    const int n0 = blockIdx.y * 256;
    const int wr = wid >> 2;       // 0..1  (M wave)
    const int wc = wid & 3;        // 0..3  (N wave)
    const int lrow = lane & 15;
    const int quad = lane >> 4;

    // reader-side swizzled 16B chunk: rotate by (row>>1)&3 (0-conflict, r2-verified)
    const int rco   = ((quad + ((lrow >> 1) & 3)) & 3) * 8;   // shorts
    const int a_off = wr * 4096 + lrow * 32 + rco;   // + qm*2048 + i*512
    const int b_off = wc * 2048 + lrow * 32 + rco;   // + j*512 (B part +8192)

    // staging: instr covers 16 LDS rows (1024B linear); lane l -> row l>>2,
    // chunk l&3. Global source pre-rotated: chunk_g = (c - (row>>1)) & 3.
    const int srow = wid * 32 + (lane >> 2);
    const int gk   = (((lane & 3) - (lane >> 3)) & 3) * 8;
    const bf16* srcA0 = Ab + (long)(m0 + srow) * lda + gk;
    const bf16* srcA1 = Ab + (long)(m0 + srow + 16) * lda + gk;
    const bf16* srcB0 = Bb + (long)(n0 + srow) * ldb + gk;
    const bf16* srcB1 = Bb + (long)(n0 + srow + 16) * ldb + gk;
    const int dst0 = wid * 1024 + lane * 8;          // shorts

    frag_cd acc[8][4] = {};
    frag_ab A0[4], A1[4], B0[4], B1[4];   // double-buffered fragments

#define STG(SLOT, PART, K0)                                                     \
    do {                                                                        \
        load16((PART ? srcB0 : srcA0) + (K0),                                   \
               (bf16*)&lds[(SLOT) * 16384 + (PART) * 8192 + dst0]);             \
        load16((PART ? srcB1 : srcA1) + (K0),                                   \
               (bf16*)&lds[(SLOT) * 16384 + (PART) * 8192 + dst0 + 512]);       \
    } while (0)

#define LOADA(DST, SLOT, QM)                                                    \
    do {                                                                        \
        _Pragma("unroll")                                                       \
        for (int i_ = 0; i_ < 4; ++i_)                                          \
            DST[i_] = *(const frag_ab*)&lds[(SLOT) * 16384 + a_off +            \
                                            (QM) * 2048 + i_ * 512];            \
    } while (0)

#define LOADB(DST, SLOT)                                                        \
    do {                                                                        \
        _Pragma("unroll")                                                       \
        for (int j_ = 0; j_ < 4; ++j_)                                          \
            DST[j_] = *(const frag_ab*)&lds[(SLOT) * 16384 + 8192 + b_off +     \
                                            j_ * 512];                          \
    } while (0)

#define MFMA16(AR, BR, QM)                                                      \
    do {                                                                        \
        _Pragma("unroll")                                                       \
        for (int i_ = 0; i_ < 4; ++i_)                                          \
            _Pragma("unroll")                                                   \
            for (int j_ = 0; j_ < 4; ++j_)                                      \
                acc[(QM) * 4 + i_][j_] = __builtin_amdgcn_mfma_f32_16x16x32_bf16( \
                    AR[i_], BR[j_], acc[(QM) * 4 + i_][j_], 0, 0, 0);           \
    } while (0)

#define VMW(N)                                                                  \
    do {                                                                        \
        if ((N) == 6)      asm volatile("s_waitcnt vmcnt(6)" ::: "memory");     \
        else if ((N) == 4) asm volatile("s_waitcnt vmcnt(4)" ::: "memory");     \
        else if ((N) == 0) asm volatile("s_waitcnt vmcnt(0)" ::: "memory");     \
    } while (0)

// Phase: issue batch p+1 (ISSUE: 1=A only, 2=A+B) -> stage -> MFMA cluster p
// (compiler-counted lgkm on entry) -> optional vmcnt -> single end barrier.
#define PH(AR, BR, QM, ISSUE, NSLOT, NAR, NBR, NQM, DO_STG, SSLOT, SPART, SK0, VMN) \
    do {                                                                        \
        if ((ISSUE) >= 1) LOADA(NAR, NSLOT, NQM);                               \
        if ((ISSUE) == 2) LOADB(NBR, NSLOT);                                    \
        if (DO_STG) STG(SSLOT, SPART, SK0);                                     \
        __builtin_amdgcn_sched_barrier(0);                                      \
        __builtin_amdgcn_s_setprio(1);                                          \
        MFMA16(AR, BR, QM);                                                     \
        __builtin_amdgcn_s_setprio(0);                                          \
        __builtin_amdgcn_sched_barrier(0);                                      \
        VMW(VMN);                                                               \
        __builtin_amdgcn_s_barrier();                                           \
        __builtin_amdgcn_sched_barrier(0);                                      \
    } while (0)

    // prologue: slot0 = tile0 ks0, slot1 = tile0 ks1, slot2 = tile1 ks0
    STG(0, 0, 0);  STG(0, 1, 0);
    STG(1, 0, 32); STG(1, 1, 32);
    STG(2, 0, 64); STG(2, 1, 64);
    asm volatile("s_waitcnt vmcnt(8)" ::: "memory");   // slot0 landed
    __builtin_amdgcn_sched_barrier(0);
    __builtin_amdgcn_s_barrier();
    __builtin_amdgcn_sched_barrier(0);
    LOADA(A0, 0, 0);      // batch 0 (cluster 0)
    LOADB(B0, 0);

    const int NI = K >> 7;   // 128 K per iteration (2 K-tiles); NI >= 2 here
    for (int it = 0; it < NI - 1; ++it) {
        const int kb = it << 7;
        //  cur    QM IS NS nxt      NQ STG SS SP SK0      VM
        PH(A0, B0, 0, 1, 0, A1, B1, 1, 1, 3, 0, kb + 96,   6);
        PH(A1, B0, 1, 2, 1, A0, B1, 0, 1, 3, 1, kb + 96,  -1);
        PH(A0, B1, 0, 1, 1, A1, B0, 1, 1, 0, 0, kb + 128,  6);
        PH(A1, B1, 1, 2, 2, A0, B0, 0, 1, 0, 1, kb + 128, -1);
        PH(A0, B0, 0, 1, 2, A1, B1, 1, 1, 1, 0, kb + 160,  6);
        PH(A1, B0, 1, 2, 3, A0, B1, 0, 1, 1, 1, kb + 160, -1);
        PH(A0, B1, 0, 1, 3, A1, B0, 1, 1, 2, 0, kb + 192,  6);
        PH(A1, B1, 1, 2, 0, A0, B0, 0, 1, 2, 1, kb + 192, -1);
    }
    {   // peeled last iteration: only slot3 (ks1 of last tile) still staged
        const int kb = (NI - 1) << 7;
        PH(A0, B0, 0, 1, 0, A1, B1, 1, 1, 3, 0, kb + 96,   6);
        PH(A1, B0, 1, 2, 1, A0, B1, 0, 1, 3, 1, kb + 96,  -1);
        PH(A0, B1, 0, 1, 1, A1, B0, 1, 0, 0, 0, 0,         4);
        PH(A1, B1, 1, 2, 2, A0, B0, 0, 0, 0, 0, 0,        -1);
        PH(A0, B0, 0, 1, 2, A1, B1, 1, 0, 0, 0, 0,         0);
        PH(A1, B0, 1, 2, 3, A0, B1, 0, 0, 0, 0, 0,        -1);
        PH(A0, B1, 0, 1, 3, A1, B0, 1, 0, 0, 0, 0,        -1);
        PH(A1, B1, 1, 0, 0, A0, B0, 0, 0, 0, 0, 0,        -1);
    }
#undef PH
#undef VMW
#undef MFMA16
#undef LOADB
#undef LOADA
#undef STG

    // epilogue: C/D layout col=lane&15, row=quad*4+reg  [m89-verified]
#pragma unroll
    for (int j = 0; j < 4; ++j) {
        const int col = n0 + wc * 64 + j * 16 + lrow;
        const float bv = HAS_BIAS ? bias[col] : 0.0f;
        const bool msk = MASK ? (maskb[col] != 0) : false;
#pragma unroll
        for (int ai = 0; ai < 8; ++ai) {
            const int rbase = m0 + wr * 128 + ai * 16 + quad * 4;
#pragma unroll
            for (int r = 0; r < 4; ++r) {
                float v = acc[ai][j][r] * scale + bv;
                if (MASK && msk) v = -INFINITY;
                st_c(&Cb[(long)(rbase + r) * ldc + col], v);
            }
        }
    }
}

// fp32 X[b][s][h] -> bf16 Xb[b][s][h] and bf16 XT[b][h][s], 64x64 tiles.
__global__ __launch_bounds__(256)
void convert_transpose(const float* __restrict__ X, bf16* __restrict__ Xb,
                       bf16* __restrict__ XT, int S, int H)
{
    __shared__ unsigned short tile[64][72];
    const int b = blockIdx.z;
    const float* Xp = X + (long)b * S * H;
    bf16* Xbp = Xb + (long)b * S * H;
    bf16* XTp = XT + (long)b * H * S;
    const int h0 = blockIdx.x * 64, s0 = blockIdx.y * 64;
    const int t = threadIdx.x;
    const int r  = t >> 4;
    const int c4 = (t & 15) * 4;

#pragma unroll
    for (int p = 0; p < 4; ++p) {
        const int row = r + p * 16;
        const float4 v = *(const float4*)&Xp[(long)(s0 + row) * H + h0 + c4];
        ushort4 u;
        u.x = f2bu(v.x); u.y = f2bu(v.y); u.z = f2bu(v.z); u.w = f2bu(v.w);
        *(ushort4*)&tile[row][c4] = u;
        *(ushort4*)&Xbp[(long)(s0 + row) * H + h0 + c4] = u;
    }
    __syncthreads();
#pragma unroll
    for (int p = 0; p < 4; ++p) {
        const int hrow = r + p * 16;
        ushort4 u;
        u.x = tile[c4 + 0][hrow];
        u.y = tile[c4 + 1][hrow];
        u.z = tile[c4 + 2][hrow];
        u.w = tile[c4 + 3][hrow];
        *(ushort4*)&XTp[(long)(h0 + hrow) * S + s0 + c4] = u;
    }
}

// both weight matrices -> bf16, contiguous out [2*H*H]
__global__ __launch_bounds__(256)
void convert_w2(const float* __restrict__ wa, const float* __restrict__ wb,
                bf16* __restrict__ out, int n4each)
{
    const int i = blockIdx.x * 256 + threadIdx.x;
    const bool second = i >= n4each;
    const float* src = second ? wb : wa;
    const int j = second ? i - n4each : i;
    const float4 v = ((const float4*)src)[j];
    ushort4 u;
    u.x = f2bu(v.x); u.y = f2bu(v.y); u.z = f2bu(v.z); u.w = f2bu(v.w);
    ((ushort4*)out)[i] = u;
}

__global__ __launch_bounds__(256)
void pack_bias(const float* __restrict__ qb, const float* __restrict__ kb,
               float* __restrict__ out, int H)
{
    const int i = blockIdx.x * 256 + threadIdx.x;
    out[i] = (i < H) ? qb[i] : kb[i - H];
}

// In-place masked softmax over rows (Slen=2048 bf16). Mask pre-applied as -inf.
__global__ __launch_bounds__(256)
void softmax_kernel(bf16* __restrict__ Smat, int Slen)
{
    const int row = blockIdx.x;
    bf16* srow = Smat + (long)row * Slen;

    const int t    = threadIdx.x;
    const int lane = t & 63;
    const int wid  = t >> 6;

    ushort4 u0 = ((const ushort4*)srow)[t * 2];
    ushort4 u1 = ((const ushort4*)srow)[t * 2 + 1];

    float vals[8];
    {
        const unsigned short us[8] = {u0.x, u0.y, u0.z, u0.w, u1.x, u1.y, u1.z, u1.w};
#pragma unroll
        for (int i = 0; i < 8; ++i) {
            unsigned int w = (unsigned int)us[i] << 16;
            vals[i] = *(float*)&w;
        }
    }

    float mx = vals[0];
#pragma unroll
    for (int i = 1; i < 8; ++i) mx = fmaxf(mx, vals[i]);

    __shared__ float red[4];
#pragma unroll
    for (int o = 32; o > 0; o >>= 1) mx = fmaxf(mx, __shfl_xor(mx, o, 64));
    if (lane == 0) red[wid] = mx;
    __syncthreads();
    mx = fmaxf(fmaxf(red[0], red[1]), fmaxf(red[2], red[3]));
    __syncthreads();

    float sum = 0.0f;
#pragma unroll
    for (int i = 0; i < 8; ++i) {
        const float e = __expf(vals[i] - mx);   // exp(-inf - mx) = 0
        vals[i] = e;
        sum += e;
    }
#pragma unroll
    for (int o = 32; o > 0; o >>= 1) sum += __shfl_xor(sum, o, 64);
    if (lane == 0) red[wid] = sum;
    __syncthreads();
    sum = red[0] + red[1] + red[2] + red[3];

    const float inv = 1.0f / sum;
    ushort4 o0, o1;
    o0.x = f2bu(vals[0] * inv); o0.y = f2bu(vals[1] * inv);
    o0.z = f2bu(vals[2] * inv); o0.w = f2bu(vals[3] * inv);
    o1.x = f2bu(vals[4] * inv); o1.y = f2bu(vals[5] * inv);
    o1.z = f2bu(vals[6] * inv); o1.w = f2bu(vals[7] * inv);
    ((ushort4*)srow)[t * 2]     = o0;
    ((ushort4*)srow)[t * 2 + 1] = o1;
}

extern "C" void kernel_launch(void* const* d_in, const int* in_sizes, int n_in,
                              void* d_out, int out_size, void* d_ws, size_t ws_size,
                              hipStream_t stream)
{
    const float* hidden = (const float*)d_in[0];
    const int*   mask   = (const int*)d_in[1];
    const float* Wq_w   = (const float*)d_in[2];
    const float* Wq_b   = (const float*)d_in[3];
    const float* Wk_w   = (const float*)d_in[4];
    const float* Wk_b   = (const float*)d_in[5];
    float* out = (float*)d_out;

    const int B = 8, S = 2048, H = 1024;
    const int M = B * S;               // 16384
    const long MH = (long)M * H;       // 16.7M elems

    // ws (bf16 elems): QK[M][2H] (67MB) | XbT (33.5MB) | Sb (67MB)
    // Xb + Wb (stacked weights) + packed bias aliased inside Sb (dead before scores).
    bf16* QK  = (bf16*)d_ws;
    bf16* XbT = QK + MH * 2;
    bf16* Sb  = XbT + MH;
    bf16* Xb  = Sb;                    // aliased
    bf16* Wb  = Xb + MH;               // [2H][H] = Wq stacked on Wk
    float* biasP = (float*)(Wb + 2L * H * H);  // 2048 floats

    const dim3 blk(256);
    const dim3 blk512(512);

    convert_transpose<<<dim3(H / 64, S / 64, B), blk, 0, stream>>>(hidden, Xb, XbT, S, H);
    convert_w2<<<dim3(2 * H * H / 1024), blk, 0, stream>>>(Wq_w, Wk_w, Wb, H * H / 4);
    pack_bias<<<dim3(2 * H / 256), blk, 0, stream>>>(Wq_b, Wk_b, biasP, H);

    // QK = Xb @ [Wq;Wk]^T + [bq;bk]   (merged, N = 2H) : 16384 x 2048, K=1024
    gemm8p<bf16, true, false><<<dim3(M / 256, 2 * H / 256, 1), blk512, 0, stream>>>(
        Xb, Wb, biasP, nullptr, QK, H, H, H, 2 * H, 0, 0, 0, 0, 1.0f);

    // Scores_b = (Q_b @ K_b^T)/32, mask applied as -inf in epilogue : 2048x2048, K=1024
    gemm8p<bf16, false, true><<<dim3(S / 256, S / 256, B), blk512, 0, stream>>>(
        QK, QK + H, nullptr, mask, Sb, H, 2 * H, 2 * H, S,
        (long)S * 2 * H, (long)S * 2 * H, (long)S * S, S, 1.0f / 32.0f);

    // softmax in place (mask already -inf)
    softmax_kernel<<<dim3(B * S), blk, 0, stream>>>(Sb, S);

    // Out_b = P_b @ X_b  (B operand = XbT, k-contig) : 2048x1024, K=2048
    gemm8p<float, false, false><<<dim3(S / 256, H / 256, B), blk512, 0, stream>>>(
        Sb, XbT, nullptr, nullptr, out, S, S, S, H,
        (long)S * S, (long)H * S, (long)S * H, 0, 1.0f);
}